// Round 6
// baseline (221.096 us; speedup 1.0000x reference)
//
#include <hip/hip_runtime.h>
#include <math.h>

#define LSEQ  512
#define BT    128
#define INF   512
#define HH    60
#define NSTEP 1536   // 3*LSEQ
#define CH2   6      // steps per lane in scan kernel: 1536 / 256

#define SROW  522    // LDS W row stride in bf16: 261 dwords == 5 (mod 32) -> ~2-way banks

typedef __attribute__((ext_vector_type(8))) short bf16x8;
typedef __attribute__((ext_vector_type(4))) float floatx4;

// ---------- packed bf16 split via v_cvt_pk_bf16_f32 (RNE, 1 instr / 2 elts) -
__device__ __forceinline__ unsigned cvt_pk_bf16(float lo, float hi) {
  unsigned r;
  asm("v_cvt_pk_bf16_f32 %0, %1, %2" : "=v"(r) : "v"(lo), "v"(hi));
  return r;  // D[15:0]=bf16(lo), D[31:16]=bf16(hi)
}
__device__ __forceinline__ void split_pair(float a0, float a1,
                                           unsigned& hw, unsigned& lw) {
  hw = cvt_pk_bf16(a0, a1);
  float h0 = __uint_as_float(hw << 16);
  float h1 = __uint_as_float(hw & 0xFFFF0000u);
  lw = cvt_pk_bf16(a0 - h0, a1 - h1);
}

// ---------- forced-issue global load (compiler cannot sink/defer this) ------
#define GLOAD(dst, ptr, voff) \
  asm volatile("global_load_dwordx4 %0, %1, %2" \
               : "=v"(dst) : "v"(voff), "s"(ptr))

#define WAIT_VM(n) \
  do { asm volatile("s_waitcnt vmcnt(" #n ")" ::: "memory"); \
       __builtin_amdgcn_sched_barrier(0); } while (0)

// ---------- kernel 1: split-bf16 MFMA GEMM + softmax + torsion angles ------
// Whole split-W (64 x 512, h+l bf16, SROW-padded) lives in LDS: 133 KB ->
// 1 block/CU, 512 threads (8 waves, 2/SIMD). W is staged ONCE (forced GLOAD
// burst), one barrier, then the K/M loop is BARRIER-FREE: each wave owns
// 2 x 16 rows and runs a flat 32-slot stream (2 groups x 16 K-steps) with a
// depth-4 rolling asm prefetch ring (10 loads in flight, vmcnt(8) steady).
// R5's per-stage W-wait + 8 barrier lockstep is gone entirely.
// acc += Ah*Bh + Ah*Bl + Al*Bh  (split-fp32, ~2^-17 relative).
__global__ __launch_bounds__(512, 2) void k_phi(
    const float* __restrict__ inp, const float* __restrict__ W,
    const float* __restrict__ bias, const float* __restrict__ alphabet,
    float* __restrict__ phi_out) {
  __shared__ unsigned short BhL[64 * SROW];   // 66816 B
  __shared__ unsigned short BlL[64 * SROW];   // 66816 B
  __shared__ float sS[HH * 3], sC[HH * 3], sBias[64];

  const int tid  = threadIdx.x;
  const int lane = tid & 63;
  const int wid  = tid >> 6;         // 0..7
  const int c    = lane & 15;        // frag row/col index
  const int quad = lane >> 4;        // 0..3
  const int row0 = blockIdx.x * 256; // block owns 256 rows

  if (tid < HH * 3) { float a = alphabet[tid]; sS[tid] = __sinf(a); sC[tid] = __cosf(a); }
  if (tid >= 192 && tid < 256) { int n = tid - 192; sBias[n] = (n < HH) ? bias[n] : 0.f; }

  // ---- prologue: stage ALL of W (60 rows x 512) split into LDS, once ----
  // 60 rows = 15 iters x (512 thr x 4 floats) ; rows 60..63 zeroed.
  {
    const unsigned voffW = ((unsigned)(tid >> 7) * INF + (tid & 127) * 4) * 4u;
    floatx4 Wb[15];
#pragma unroll
    for (int i = 0; i < 15; ++i)
      GLOAD(Wb[i], W + (size_t)i * 4 * INF, voffW);
    const int rb = tid >> 7;          // 0..3
    const int j4 = (tid & 127) * 4;   // 0..508
    WAIT_VM(7);
#pragma unroll
    for (int i = 0; i < 8; ++i) {
      unsigned h01, l01, h23, l23;
      split_pair(Wb[i][0], Wb[i][1], h01, l01);
      split_pair(Wb[i][2], Wb[i][3], h23, l23);
      const int r = i * 4 + rb;
      *(uint2*)&BhL[r * SROW + j4] = make_uint2(h01, h23);
      *(uint2*)&BlL[r * SROW + j4] = make_uint2(l01, l23);
    }
    WAIT_VM(0);
#pragma unroll
    for (int i = 8; i < 15; ++i) {
      unsigned h01, l01, h23, l23;
      split_pair(Wb[i][0], Wb[i][1], h01, l01);
      split_pair(Wb[i][2], Wb[i][3], h23, l23);
      const int r = i * 4 + rb;
      *(uint2*)&BhL[r * SROW + j4] = make_uint2(h01, h23);
      *(uint2*)&BlL[r * SROW + j4] = make_uint2(l01, l23);
    }
    for (int z = tid; z < 4 * SROW; z += 512) {   // rows 60..63 = 0
      BhL[60 * SROW + z] = 0;
      BlL[60 * SROW + z] = 0;
    }
  }
  __syncthreads();    // the ONLY barrier

  // ---- barrier-free K/M loop: 2 row-groups x 16 K-steps = 32 flat slots ----
  floatx4 acc[2][4];
#pragma unroll
  for (int g = 0; g < 2; ++g)
#pragma unroll
    for (int nt = 0; nt < 4; ++nt) acc[g][nt] = (floatx4){0.f, 0.f, 0.f, 0.f};

  const float* aBase = inp + (size_t)row0 * INF;
  unsigned voffA[2];
#pragma unroll
  for (int g = 0; g < 2; ++g)
    voffA[g] = ((unsigned)(wid * 32 + g * 16 + c) * INF + quad * 8) * 4u;

  floatx4 PF[5][2];   // ring, indexed i%5 (compile-time after unroll)

  // prologue: slots 0..3 in flight (8 loads)
#pragma unroll
  for (int j = 0; j < 4; ++j) {
    const int g = j >> 4, ks = j & 15;
    GLOAD(PF[j % 5][0], aBase + ks * 32,     voffA[g]);
    GLOAD(PF[j % 5][1], aBase + ks * 32 + 4, voffA[g]);
  }

#pragma unroll
  for (int i = 0; i < 32; ++i) {
    if (i + 4 < 32) {
      const int j = i + 4, g = j >> 4, ks = j & 15;
      GLOAD(PF[j % 5][0], aBase + ks * 32,     voffA[g]);
      GLOAD(PF[j % 5][1], aBase + ks * 32 + 4, voffA[g]);
    }
    if (i < 28)       WAIT_VM(8);
    else if (i == 28) WAIT_VM(6);
    else if (i == 29) WAIT_VM(4);
    else if (i == 30) WAIT_VM(2);
    else              WAIT_VM(0);

    const int g  = i >> 4;
    const int ks = i & 15;
    floatx4 x = PF[i % 5][0], y = PF[i % 5][1];
    uint4 uh, ul;
    split_pair(x[0], x[1], uh.x, ul.x);
    split_pair(x[2], x[3], uh.y, ul.y);
    split_pair(y[0], y[1], uh.z, ul.z);
    split_pair(y[2], y[3], uh.w, ul.w);
    bf16x8 Ah = __builtin_bit_cast(bf16x8, uh);
    bf16x8 Al = __builtin_bit_cast(bf16x8, ul);
#pragma unroll
    for (int nt = 0; nt < 4; ++nt) {
      const int boff = (nt * 16 + c) * SROW + ks * 32 + quad * 8;
      bf16x8 Bh = *(const bf16x8*)&BhL[boff];
      bf16x8 Bl = *(const bf16x8*)&BlL[boff];
      acc[g][nt] = __builtin_amdgcn_mfma_f32_16x16x32_bf16(Ah, Bh, acc[g][nt], 0, 0, 0);
      acc[g][nt] = __builtin_amdgcn_mfma_f32_16x16x32_bf16(Ah, Bl, acc[g][nt], 0, 0, 0);
      acc[g][nt] = __builtin_amdgcn_mfma_f32_16x16x32_bf16(Al, Bh, acc[g][nt], 0, 0, 0);
    }
  }

  // ---- epilogue: C/D layout row = quad*4+reg, col = lane&15 ----
#pragma unroll
  for (int g = 0; g < 2; ++g) {
#pragma unroll
    for (int reg = 0; reg < 4; ++reg) {
      float lg[4];  bool val[4];
#pragma unroll
      for (int nt = 0; nt < 4; ++nt) {
        const int n = nt * 16 + c;
        val[nt] = (n < HH);
        lg[nt] = acc[g][nt][reg] + sBias[n];
      }
      float m = -1e30f;
#pragma unroll
      for (int nt = 0; nt < 4; ++nt) if (val[nt]) m = fmaxf(m, lg[nt]);
#pragma unroll
      for (int d = 1; d < 16; d <<= 1) m = fmaxf(m, __shfl_xor(m, d, 64));

      float s0=0.f,c0=0.f,s1=0.f,c1=0.f,s2=0.f,c2=0.f;
#pragma unroll
      for (int nt = 0; nt < 4; ++nt) {
        const int n = nt * 16 + c;
        float e = val[nt] ? __expf(lg[nt] - m) : 0.f;
        s0 = fmaf(e, sS[n*3+0], s0);  c0 = fmaf(e, sC[n*3+0], c0);
        s1 = fmaf(e, sS[n*3+1], s1);  c1 = fmaf(e, sC[n*3+1], c1);
        s2 = fmaf(e, sS[n*3+2], s2);  c2 = fmaf(e, sC[n*3+2], c2);
      }
#pragma unroll
      for (int d = 1; d < 16; d <<= 1) {
        s0 += __shfl_xor(s0, d, 64);  c0 += __shfl_xor(c0, d, 64);
        s1 += __shfl_xor(s1, d, 64);  c1 += __shfl_xor(c1, d, 64);
        s2 += __shfl_xor(s2, d, 64);  c2 += __shfl_xor(c2, d, 64);
      }
      if (c == 0) {
        const int row = row0 + wid * 32 + g * 16 + quad * 4 + reg;
        const int l  = row >> 7;        // / BT
        const int bb = row & 127;       // % BT
        float* pp = phi_out + (size_t)bb * NSTEP + 3 * l;
        pp[0] = atan2f(s0, c0);
        pp[1] = atan2f(s1, c1);
        pp[2] = atan2f(s2, c2);
      }
    }
  }
}

// ---------- rigid transform (3x3 rotation row-major + translation) ----------
struct Xf { float r[9]; float p[3]; };

__device__ __forceinline__ Xf compose(const Xf& A, const Xf& B) {
  Xf o;
#pragma unroll
  for (int i = 0; i < 3; ++i) {
#pragma unroll
    for (int j = 0; j < 3; ++j) {
      o.r[i*3+j] = fmaf(A.r[i*3+0], B.r[0+j],
                   fmaf(A.r[i*3+1], B.r[3+j],
                        A.r[i*3+2] * B.r[6+j]));
    }
    o.p[i] = fmaf(A.r[i*3+0], B.p[0],
             fmaf(A.r[i*3+1], B.p[1],
             fmaf(A.r[i*3+2], B.p[2], A.p[i])));
  }
  return o;
}

__device__ __forceinline__ Xf make_T(float phi, float st, float ct, float r) {
  float sp = __sinf(phi), cp = __cosf(phi);
  Xf T;
  T.r[0] = ct;      T.r[1] = -st;     T.r[2] = 0.f;
  T.r[3] = cp * st; T.r[4] = ct * cp; T.r[5] = -sp;
  T.r[6] = sp * st; T.r[7] = ct * sp; T.r[8] = cp;
  T.p[0] = r * ct;  T.p[1] = r * T.r[3]; T.p[2] = r * T.r[6];
  return T;
}

__device__ __forceinline__ void set_identity(Xf& X) {
  X.r[0]=1.f; X.r[1]=0.f; X.r[2]=0.f;
  X.r[3]=0.f; X.r[4]=1.f; X.r[5]=0.f;
  X.r[6]=0.f; X.r[7]=0.f; X.r[8]=1.f;
  X.p[0]=0.f; X.p[1]=0.f; X.p[2]=0.f;
}

// ---------- kernel 2: two-level parallel rigid-transform scan ---------------
__global__ __launch_bounds__(256) void k_scan(
    const float* __restrict__ phi, const float* __restrict__ bl,
    const float* __restrict__ ba, float* __restrict__ out) {
  __shared__ Xf wt[4];

  const int b = blockIdx.x;       // chain 0..127
  const int t = threadIdx.x & 63; // lane in wave
  const int w = threadIdx.x >> 6; // wave 0..3
  const int g = threadIdx.x;      // global lane 0..255

  float st[3], ct[3], rr[3];
#pragma unroll
  for (int j = 0; j < 3; ++j) {
    float a = ba[j];
    st[j] = __sinf(a); ct[j] = __cosf(a); rr[j] = bl[j];
  }

  // steps for this lane: g*6 .. g*6+5 ; (g*6+s)%3 == s%3 since 6%3==0
  float f[CH2];
  const float2* ph2 = (const float2*)(phi + (size_t)b * NSTEP + g * CH2);
#pragma unroll
  for (int q = 0; q < CH2/2; ++q) {
    float2 v = ph2[q];
    f[2*q+0] = v.x; f[2*q+1] = v.y;
  }

  Xf Q = make_T(f[0], st[0], ct[0], rr[0]);
#pragma unroll
  for (int s = 1; s < CH2; ++s)
    Q = compose(Q, make_T(f[s], st[s%3], ct[s%3], rr[s%3]));

  // wave-level inclusive scan (left-compose earlier lanes)
#pragma unroll
  for (int d = 1; d < 64; d <<= 1) {
    Xf O;
#pragma unroll
    for (int q = 0; q < 9; ++q) O.r[q] = __shfl_up(Q.r[q], d, 64);
#pragma unroll
    for (int q = 0; q < 3; ++q) O.p[q] = __shfl_up(Q.p[q], d, 64);
    if (t < d) set_identity(O);
    Q = compose(O, Q);
  }

  // cross-wave totals
  if (t == 63) wt[w] = Q;
  __syncthreads();

  // wave-local exclusive prefix
  Xf E;
#pragma unroll
  for (int q = 0; q < 9; ++q) E.r[q] = __shfl_up(Q.r[q], 1, 64);
#pragma unroll
  for (int q = 0; q < 3; ++q) E.p[q] = __shfl_up(Q.p[q], 1, 64);
  if (t == 0) set_identity(E);

  Xf S0;
  S0.r[0] = 0.f;                  S0.r[1] = 0.816496580927726f;   S0.r[2] = 0.5773502691896258f;
  S0.r[3] = -0.7071067811865475f; S0.r[4] = -0.4082482904638631f; S0.r[5] = 0.5773502691896258f;
  S0.r[6] = 0.7071067811865475f;  S0.r[7] = -0.4082482904638631f; S0.r[8] = 0.5773502691896258f;
  S0.p[0] = 0.f; S0.p[1] = 0.f; S0.p[2] = 1.f;

  // SP = S0 ∘ (wt[0] ∘ ... ∘ wt[w-1])  (wave-uniform, <=3 composes)
  Xf SP = S0;
#pragma unroll
  for (int i = 0; i < 3; ++i)
    if (i < w) SP = compose(SP, wt[i]);

  Xf cur = compose(SP, E);

  float* op = out + (size_t)(g * CH2) * (BT * 3) + b * 3;
#pragma unroll
  for (int s = 0; s < CH2; ++s) {
    cur = compose(cur, make_T(f[s], st[s%3], ct[s%3], rr[s%3]));
    op[(size_t)s * (BT*3) + 0] = cur.p[0];
    op[(size_t)s * (BT*3) + 1] = cur.p[1];
    op[(size_t)s * (BT*3) + 2] = cur.p[2];
  }
}

// ---------- launch ---------------------------------------------------------
extern "C" void kernel_launch(void* const* d_in, const int* in_sizes, int n_in,
                              void* d_out, int out_size, void* d_ws, size_t ws_size,
                              hipStream_t stream) {
  const float* inp      = (const float*)d_in[0];
  const float* W        = (const float*)d_in[1];
  const float* bias     = (const float*)d_in[2];
  const float* alphabet = (const float*)d_in[3];
  const float* bl       = (const float*)d_in[4];
  const float* ba       = (const float*)d_in[5];
  float* out = (float*)d_out;

  float* phi = (float*)d_ws;   // 786432 B

  k_phi<<<dim3(256), dim3(512), 0, stream>>>(inp, W, bias, alphabet, phi);
  k_scan<<<dim3(BT), dim3(256), 0, stream>>>(phi, bl, ba, out);
}

// Round 7
// 212.458 us; speedup vs baseline: 1.0407x; 1.0407x over previous
//
#include <hip/hip_runtime.h>
#include <math.h>

#define LSEQ  512
#define BT    128
#define INF   512
#define HH    60
#define NSTEP 1536   // 3*LSEQ
#define CH2   6      // steps per lane in scan kernel: 1536 / 256

#define MTILE 64     // rows per block (k_phi); wave owns 16 rows
#define KSTG  128    // K extent staged per stage (4 stages of 128)
#define BROW  136    // LDS B row stride in bf16 (128 + 8 pad; 16B-aligned rows)

typedef __attribute__((ext_vector_type(8))) short bf16x8;
typedef __attribute__((ext_vector_type(4))) float floatx4;

// ---------- packed bf16 split via v_cvt_pk_bf16_f32 (RNE, 1 instr / 2 elts) -
__device__ __forceinline__ unsigned cvt_pk_bf16(float lo, float hi) {
  unsigned r;
  asm("v_cvt_pk_bf16_f32 %0, %1, %2" : "=v"(r) : "v"(lo), "v"(hi));
  return r;  // D[15:0]=bf16(lo), D[31:16]=bf16(hi)
}
__device__ __forceinline__ void split_pair(float a0, float a1,
                                           unsigned& hw, unsigned& lw) {
  hw = cvt_pk_bf16(a0, a1);
  float h0 = __uint_as_float(hw << 16);
  float h1 = __uint_as_float(hw & 0xFFFF0000u);
  lw = cvt_pk_bf16(a0 - h0, a1 - h1);
}

// ---------- forced-issue global load (compiler cannot sink/defer this) ------
#define GLOAD(dst, ptr, voff) \
  asm volatile("global_load_dwordx4 %0, %1, %2" \
               : "=v"(dst) : "v"(voff), "s"(ptr))

#define WAIT_VM(n) \
  do { asm volatile("s_waitcnt vmcnt(" #n ")" ::: "memory"); \
       __builtin_amdgcn_sched_barrier(0); } while (0)

// raw barrier: drains LDS only, NOT vmcnt (keeps global pipeline alive) -----
#define BARRIER() \
  do { asm volatile("s_waitcnt lgkmcnt(0)" ::: "memory"); \
       __builtin_amdgcn_s_barrier(); \
       asm volatile("" ::: "memory"); } while (0)

// ---------- kernel 1: split-bf16 MFMA GEMM + softmax + torsion angles ------
// R5 skeleton (MTILE=64, 36KB LDS, 3 blocks/CU) + fully covered pipeline:
//  - A: rolling 4-slot asm ring, SEAMLESS across stage boundaries
//  - W: issued one full stage ahead (right after SPLIT_W frees the regs)
// FIFO queue per stage s: [W(s) 8][A slots 4s..4s+3 8] -> entry WAIT_VM(8)
// completes W(s); per step j: issue slot j+4, WAIT_VM(16) completes slot j
// (newer = W(s+1) 8 + slots j+1..j+4 8). No wait ever drains to 0 until the
// tail. acc += Ah*Bh + Ah*Bl + Al*Bh  (split-fp32, ~2^-17 relative).

#define ISSUE_A_SLOT(J) \
  { GLOAD(PF[(J) % 5][0], aBase + (J) * 32,     voffA); \
    GLOAD(PF[(J) % 5][1], aBase + (J) * 32 + 4, voffA); }

#define ISSUE_W(KB) \
  { _Pragma("unroll") \
    for (int i_ = 0; i_ < 7; ++i_) \
      GLOAD(Wb[i_], W + (KB) + i_*4096, voffW); \
    GLOAD(Wb[7], W + (KB) + 7*4096, voffWc); }

#define SPLIT_W() \
  { _Pragma("unroll") \
    for (int i_ = 0; i_ < 8; ++i_) { \
      const int chunk_ = i_ * 256 + tid; \
      const int r_  = chunk_ >> 5; \
      const int j4_ = (chunk_ & 31) * 4; \
      floatx4 wv_ = Wb[i_]; \
      if (i_ == 7 && tid >= 128) wv_ = (floatx4){0.f, 0.f, 0.f, 0.f}; \
      unsigned h01_, l01_, h23_, l23_; \
      split_pair(wv_[0], wv_[1], h01_, l01_); \
      split_pair(wv_[2], wv_[3], h23_, l23_); \
      *(uint2*)&BhL[r_ * BROW + j4_] = make_uint2(h01_, h23_); \
      *(uint2*)&BlL[r_ * BROW + j4_] = make_uint2(l01_, l23_); } }

__global__ __launch_bounds__(256, 3) void k_phi(
    const float* __restrict__ inp, const float* __restrict__ W,
    const float* __restrict__ bias, const float* __restrict__ alphabet,
    float* __restrict__ phi_out) {
  __shared__ unsigned short BhL[64 * BROW];   // 17408 B
  __shared__ unsigned short BlL[64 * BROW];   // 17408 B
  __shared__ float sS[HH * 3], sC[HH * 3], sBias[64];

  const int tid  = threadIdx.x;
  const int lane = tid & 63;
  const int wid  = tid >> 6;
  const int c    = lane & 15;        // frag row/col index
  const int quad = lane >> 4;        // 0..3
  const int row0 = blockIdx.x * MTILE;

  if (tid < HH * 3) { float a = alphabet[tid]; sS[tid] = __sinf(a); sC[tid] = __cosf(a); }
  if (tid >= 192 && tid < 256) { int n = tid - 192; sBias[n] = (n < HH) ? bias[n] : 0.f; }

  floatx4 acc[4];
#pragma unroll
  for (int nt = 0; nt < 4; ++nt) acc[nt] = (floatx4){0.f, 0.f, 0.f, 0.f};

  // per-lane byte voffsets; SGPR bases carry block-uniform / constant parts
  const float* aBase = inp + (size_t)row0 * INF;
  const unsigned voffA  = ((unsigned)(wid * 16 + c) * INF + quad * 8) * 4u;
  const unsigned voffW  = ((unsigned)(tid >> 5) * INF + (tid & 31) * 4) * 4u;
  const unsigned voffWc = (tid < 128) ? voffW : 0u;  // clamp OOB W rows (i=7)

  floatx4 PF[5][2];   // A ring; indices compile-time after unroll
  floatx4 Wb[8];      // W stage buffer (single; refilled after SPLIT)

  // ---- prologue: W(0) then A slots 0..3 ----
  ISSUE_W(0);
#pragma unroll
  for (int j = 0; j < 4; ++j) ISSUE_A_SLOT(j);

#pragma unroll
  for (int s = 0; s < 4; ++s) {
    WAIT_VM(8);                 // W(s) complete; A slots 4s..4s+3 in flight
    SPLIT_W();                  // Wb -> LDS (h/l)
    if (s < 3) ISSUE_W((s + 1) * KSTG);   // refill Wb, rides a whole stage
    BARRIER();                  // publish stage-s B tile (also syncs sS/sC)

#pragma unroll
    for (int t = 0; t < 4; ++t) {
      const int j = s * 4 + t;  // global K-step 0..15
      if (j + 4 < 16) ISSUE_A_SLOT(j + 4);
      if (j <= 11)      WAIT_VM(16);   // slot j done; W(s+1)+4 slots ride
      else if (j == 12) WAIT_VM(6);
      else if (j == 13) WAIT_VM(4);
      else if (j == 14) WAIT_VM(2);
      else              WAIT_VM(0);

      floatx4 x = PF[j % 5][0], y = PF[j % 5][1];
      uint4 uh, ul;
      split_pair(x[0], x[1], uh.x, ul.x);
      split_pair(x[2], x[3], uh.y, ul.y);
      split_pair(y[0], y[1], uh.z, ul.z);
      split_pair(y[2], y[3], uh.w, ul.w);
      bf16x8 Ah = __builtin_bit_cast(bf16x8, uh);
      bf16x8 Al = __builtin_bit_cast(bf16x8, ul);
      const int kl = t * 32;
#pragma unroll
      for (int nt = 0; nt < 4; ++nt) {
        const int boff = (nt * 16 + c) * BROW + kl + quad * 8;
        bf16x8 Bh = *(const bf16x8*)&BhL[boff];
        bf16x8 Bl = *(const bf16x8*)&BlL[boff];
        acc[nt] = __builtin_amdgcn_mfma_f32_16x16x32_bf16(Ah, Bh, acc[nt], 0, 0, 0);
        acc[nt] = __builtin_amdgcn_mfma_f32_16x16x32_bf16(Ah, Bl, acc[nt], 0, 0, 0);
        acc[nt] = __builtin_amdgcn_mfma_f32_16x16x32_bf16(Al, Bh, acc[nt], 0, 0, 0);
      }
    }
    if (s < 3) BARRIER();       // stage-s B tile fully consumed
  }

  // ---- epilogue: C/D layout row = quad*4+reg, col = lane&15 ----
#pragma unroll
  for (int reg = 0; reg < 4; ++reg) {
    float lg[4];  bool val[4];
#pragma unroll
    for (int nt = 0; nt < 4; ++nt) {
      const int n = nt * 16 + c;
      val[nt] = (n < HH);
      lg[nt] = acc[nt][reg] + sBias[n];
    }
    float m = -1e30f;
#pragma unroll
    for (int nt = 0; nt < 4; ++nt) if (val[nt]) m = fmaxf(m, lg[nt]);
#pragma unroll
    for (int d = 1; d < 16; d <<= 1) m = fmaxf(m, __shfl_xor(m, d, 64));

    float s0=0.f,c0=0.f,s1=0.f,c1=0.f,s2=0.f,c2=0.f;
#pragma unroll
    for (int nt = 0; nt < 4; ++nt) {
      const int n = nt * 16 + c;
      float e = val[nt] ? __expf(lg[nt] - m) : 0.f;
      s0 = fmaf(e, sS[n*3+0], s0);  c0 = fmaf(e, sC[n*3+0], c0);
      s1 = fmaf(e, sS[n*3+1], s1);  c1 = fmaf(e, sC[n*3+1], c1);
      s2 = fmaf(e, sS[n*3+2], s2);  c2 = fmaf(e, sC[n*3+2], c2);
    }
#pragma unroll
    for (int d = 1; d < 16; d <<= 1) {
      s0 += __shfl_xor(s0, d, 64);  c0 += __shfl_xor(c0, d, 64);
      s1 += __shfl_xor(s1, d, 64);  c1 += __shfl_xor(c1, d, 64);
      s2 += __shfl_xor(s2, d, 64);  c2 += __shfl_xor(c2, d, 64);
    }
    if (c == 0) {
      const int row = row0 + wid * 16 + quad * 4 + reg;
      const int l  = row >> 7;        // / BT
      const int bb = row & 127;       // % BT
      float* pp = phi_out + (size_t)bb * NSTEP + 3 * l;
      pp[0] = atan2f(s0, c0);
      pp[1] = atan2f(s1, c1);
      pp[2] = atan2f(s2, c2);
    }
  }
}

// ---------- rigid transform (3x3 rotation row-major + translation) ----------
struct Xf { float r[9]; float p[3]; };

__device__ __forceinline__ Xf compose(const Xf& A, const Xf& B) {
  Xf o;
#pragma unroll
  for (int i = 0; i < 3; ++i) {
#pragma unroll
    for (int j = 0; j < 3; ++j) {
      o.r[i*3+j] = fmaf(A.r[i*3+0], B.r[0+j],
                   fmaf(A.r[i*3+1], B.r[3+j],
                        A.r[i*3+2] * B.r[6+j]));
    }
    o.p[i] = fmaf(A.r[i*3+0], B.p[0],
             fmaf(A.r[i*3+1], B.p[1],
             fmaf(A.r[i*3+2], B.p[2], A.p[i])));
  }
  return o;
}

__device__ __forceinline__ Xf make_T(float phi, float st, float ct, float r) {
  float sp = __sinf(phi), cp = __cosf(phi);
  Xf T;
  T.r[0] = ct;      T.r[1] = -st;     T.r[2] = 0.f;
  T.r[3] = cp * st; T.r[4] = ct * cp; T.r[5] = -sp;
  T.r[6] = sp * st; T.r[7] = ct * sp; T.r[8] = cp;
  T.p[0] = r * ct;  T.p[1] = r * T.r[3]; T.p[2] = r * T.r[6];
  return T;
}

__device__ __forceinline__ void set_identity(Xf& X) {
  X.r[0]=1.f; X.r[1]=0.f; X.r[2]=0.f;
  X.r[3]=0.f; X.r[4]=1.f; X.r[5]=0.f;
  X.r[6]=0.f; X.r[7]=0.f; X.r[8]=1.f;
  X.p[0]=0.f; X.p[1]=0.f; X.p[2]=0.f;
}

// ---------- kernel 2: two-level parallel rigid-transform scan ---------------
__global__ __launch_bounds__(256) void k_scan(
    const float* __restrict__ phi, const float* __restrict__ bl,
    const float* __restrict__ ba, float* __restrict__ out) {
  __shared__ Xf wt[4];

  const int b = blockIdx.x;       // chain 0..127
  const int t = threadIdx.x & 63; // lane in wave
  const int w = threadIdx.x >> 6; // wave 0..3
  const int g = threadIdx.x;      // global lane 0..255

  float st[3], ct[3], rr[3];
#pragma unroll
  for (int j = 0; j < 3; ++j) {
    float a = ba[j];
    st[j] = __sinf(a); ct[j] = __cosf(a); rr[j] = bl[j];
  }

  // steps for this lane: g*6 .. g*6+5 ; (g*6+s)%3 == s%3 since 6%3==0
  float f[CH2];
  const float2* ph2 = (const float2*)(phi + (size_t)b * NSTEP + g * CH2);
#pragma unroll
  for (int q = 0; q < CH2/2; ++q) {
    float2 v = ph2[q];
    f[2*q+0] = v.x; f[2*q+1] = v.y;
  }

  Xf Q = make_T(f[0], st[0], ct[0], rr[0]);
#pragma unroll
  for (int s = 1; s < CH2; ++s)
    Q = compose(Q, make_T(f[s], st[s%3], ct[s%3], rr[s%3]));

  // wave-level inclusive scan (left-compose earlier lanes)
#pragma unroll
  for (int d = 1; d < 64; d <<= 1) {
    Xf O;
#pragma unroll
    for (int q = 0; q < 9; ++q) O.r[q] = __shfl_up(Q.r[q], d, 64);
#pragma unroll
    for (int q = 0; q < 3; ++q) O.p[q] = __shfl_up(Q.p[q], d, 64);
    if (t < d) set_identity(O);
    Q = compose(O, Q);
  }

  // cross-wave totals
  if (t == 63) wt[w] = Q;
  __syncthreads();

  // wave-local exclusive prefix
  Xf E;
#pragma unroll
  for (int q = 0; q < 9; ++q) E.r[q] = __shfl_up(Q.r[q], 1, 64);
#pragma unroll
  for (int q = 0; q < 3; ++q) E.p[q] = __shfl_up(Q.p[q], 1, 64);
  if (t == 0) set_identity(E);

  Xf S0;
  S0.r[0] = 0.f;                  S0.r[1] = 0.816496580927726f;   S0.r[2] = 0.5773502691896258f;
  S0.r[3] = -0.7071067811865475f; S0.r[4] = -0.4082482904638631f; S0.r[5] = 0.5773502691896258f;
  S0.r[6] = 0.7071067811865475f;  S0.r[7] = -0.4082482904638631f; S0.r[8] = 0.5773502691896258f;
  S0.p[0] = 0.f; S0.p[1] = 0.f; S0.p[2] = 1.f;

  // SP = S0 ∘ (wt[0] ∘ ... ∘ wt[w-1])  (wave-uniform, <=3 composes)
  Xf SP = S0;
#pragma unroll
  for (int i = 0; i < 3; ++i)
    if (i < w) SP = compose(SP, wt[i]);

  Xf cur = compose(SP, E);

  float* op = out + (size_t)(g * CH2) * (BT * 3) + b * 3;
#pragma unroll
  for (int s = 0; s < CH2; ++s) {
    cur = compose(cur, make_T(f[s], st[s%3], ct[s%3], rr[s%3]));
    op[(size_t)s * (BT*3) + 0] = cur.p[0];
    op[(size_t)s * (BT*3) + 1] = cur.p[1];
    op[(size_t)s * (BT*3) + 2] = cur.p[2];
  }
}

// ---------- launch ---------------------------------------------------------
extern "C" void kernel_launch(void* const* d_in, const int* in_sizes, int n_in,
                              void* d_out, int out_size, void* d_ws, size_t ws_size,
                              hipStream_t stream) {
  const float* inp      = (const float*)d_in[0];
  const float* W        = (const float*)d_in[1];
  const float* bias     = (const float*)d_in[2];
  const float* alphabet = (const float*)d_in[3];
  const float* bl       = (const float*)d_in[4];
  const float* ba       = (const float*)d_in[5];
  float* out = (float*)d_out;

  float* phi = (float*)d_ws;   // 786432 B

  k_phi<<<dim3((LSEQ*BT)/MTILE), dim3(256), 0, stream>>>(inp, W, bias, alphabet, phi);
  k_scan<<<dim3(BT), dim3(256), 0, stream>>>(phi, bl, ba, out);
}

// Round 9
// 212.390 us; speedup vs baseline: 1.0410x; 1.0003x over previous
//
#include <hip/hip_runtime.h>
#include <math.h>

#define LSEQ  512
#define BT    128
#define INF   512
#define HH    60
#define NSTEP 1536   // 3*LSEQ
#define CH2   6      // steps per lane in scan kernel: 1536 / 256

#define MTILE 64     // rows per block (k_phi); wave owns 16 rows
#define KSTG  128    // K extent staged per stage (4 stages of 128)
#define BROW  136    // LDS B row stride in bf16 (128 + 8 pad; 16B-aligned rows)

typedef __attribute__((ext_vector_type(8))) short bf16x8;
typedef __attribute__((ext_vector_type(4))) float floatx4;

// ---------- packed bf16 split via v_cvt_pk_bf16_f32 (RNE, 1 instr / 2 elts) -
__device__ __forceinline__ unsigned cvt_pk_bf16(float lo, float hi) {
  unsigned r;
  asm("v_cvt_pk_bf16_f32 %0, %1, %2" : "=v"(r) : "v"(lo), "v"(hi));
  return r;  // D[15:0]=bf16(lo), D[31:16]=bf16(hi)
}
__device__ __forceinline__ void split_pair(float a0, float a1,
                                           unsigned& hw, unsigned& lw) {
  hw = cvt_pk_bf16(a0, a1);
  float h0 = __uint_as_float(hw << 16);
  float h1 = __uint_as_float(hw & 0xFFFF0000u);
  lw = cvt_pk_bf16(a0 - h0, a1 - h1);
}

// ---------- forced-issue global load (compiler cannot sink/defer this) ------
#define GLOAD(dst, ptr, voff) \
  asm volatile("global_load_dwordx4 %0, %1, %2" \
               : "=v"(dst) : "v"(voff), "s"(ptr))

#define WAIT_VM(n) \
  do { asm volatile("s_waitcnt vmcnt(" #n ")" ::: "memory"); \
       __builtin_amdgcn_sched_barrier(0); } while (0)

// raw barrier: drains LDS only, NOT vmcnt (keeps global pipeline alive) -----
#define BARRIER() \
  do { asm volatile("s_waitcnt lgkmcnt(0)" ::: "memory"); \
       __builtin_amdgcn_s_barrier(); \
       asm volatile("" ::: "memory"); } while (0)

// ---------- kernel 1: split-bf16 MFMA GEMM + softmax + torsion angles ------
// R9 = R8 with the FIFO hole fixed. Queue walk (verified step by step):
// prologue: [W(0) 8][A0 A1 A2 6]. Stage entry WAIT_VM(6) completes W(s).
// After ISSUE_W(s+1): [A(4s..4s+2) 6][W(s+1) 8].
//  t=0..2 (j%4<3): issue A(j+3) -> 16 outstanding; WAIT_VM(14) completes
//    A(j) (it is oldest).
//  t=3 (j=3,7,11): A(j) sits BEHIND W(s+1) in the queue -> WAIT_VM(6)
//    (completes W(s+1)+A(j), leaves the 3 lookahead slots; W(s+1) has had
//    ~3 K-steps + split + barrier of cover, so this wait is near-free).
//  tail: j=12 WAIT_VM(6), then 4/2/0.
// acc += Ah*Bh + Ah*Bl + Al*Bh (split-fp32, ~2^-17 rel).

#define ISSUE_A_SLOT(J) \
  { GLOAD(PF[(J) & 3][0], aBase + (J) * 32,     voffA); \
    GLOAD(PF[(J) & 3][1], aBase + (J) * 32 + 4, voffA); }

#define ISSUE_W(KB) \
  { _Pragma("unroll") \
    for (int i_ = 0; i_ < 7; ++i_) \
      GLOAD(Wb[i_], W + (KB) + i_*4096, voffW); \
    GLOAD(Wb[7], W + (KB) + 7*4096, voffWc); }

#define SPLIT_W() \
  { _Pragma("unroll") \
    for (int i_ = 0; i_ < 8; ++i_) { \
      const int chunk_ = i_ * 256 + tid; \
      const int r_  = chunk_ >> 5; \
      const int j4_ = (chunk_ & 31) * 4; \
      floatx4 wv_ = Wb[i_]; \
      if (i_ == 7 && tid >= 128) wv_ = (floatx4){0.f, 0.f, 0.f, 0.f}; \
      unsigned h01_, l01_, h23_, l23_; \
      split_pair(wv_[0], wv_[1], h01_, l01_); \
      split_pair(wv_[2], wv_[3], h23_, l23_); \
      *(uint2*)&BhL[r_ * BROW + j4_] = make_uint2(h01_, h23_); \
      *(uint2*)&BlL[r_ * BROW + j4_] = make_uint2(l01_, l23_); } }

__global__ __launch_bounds__(256, 4) void k_phi(
    const float* __restrict__ inp, const float* __restrict__ W,
    const float* __restrict__ bias, const float* __restrict__ alphabet,
    float* __restrict__ phi_out) {
  __shared__ unsigned short BhL[64 * BROW];   // 17408 B
  __shared__ unsigned short BlL[64 * BROW];   // 17408 B
  __shared__ float sS[HH * 3], sC[HH * 3], sBias[64];

  const int tid  = threadIdx.x;
  const int lane = tid & 63;
  const int wid  = tid >> 6;
  const int c    = lane & 15;        // frag row/col index
  const int quad = lane >> 4;        // 0..3
  const int row0 = blockIdx.x * MTILE;

  if (tid < HH * 3) { float a = alphabet[tid]; sS[tid] = __sinf(a); sC[tid] = __cosf(a); }
  if (tid >= 192 && tid < 256) { int n = tid - 192; sBias[n] = (n < HH) ? bias[n] : 0.f; }

  floatx4 acc[4];
#pragma unroll
  for (int nt = 0; nt < 4; ++nt) acc[nt] = (floatx4){0.f, 0.f, 0.f, 0.f};

  // per-lane byte voffsets; SGPR bases carry block-uniform / constant parts
  const float* aBase = inp + (size_t)row0 * INF;
  const unsigned voffA  = ((unsigned)(wid * 16 + c) * INF + quad * 8) * 4u;
  const unsigned voffW  = ((unsigned)(tid >> 5) * INF + (tid & 31) * 4) * 4u;
  const unsigned voffWc = (tid < 128) ? voffW : 0u;  // clamp OOB W rows (i=7)

  floatx4 PF[4][2];   // A ring, 3-slot lookahead; indices compile-time
  floatx4 Wb[8];      // W stage buffer (refilled one stage ahead)

  // ---- prologue: W(0) then A slots 0..2 ----
  ISSUE_W(0);
  ISSUE_A_SLOT(0); ISSUE_A_SLOT(1); ISSUE_A_SLOT(2);

#pragma unroll
  for (int s = 0; s < 4; ++s) {
    WAIT_VM(6);                 // W(s) complete; 3 A slots ride
    SPLIT_W();                  // Wb -> LDS (h/l)
    if (s < 3) ISSUE_W((s + 1) * KSTG);   // refill Wb, rides a whole stage
    BARRIER();                  // publish stage-s B tile (also syncs sS/sC)

#pragma unroll
    for (int t = 0; t < 4; ++t) {
      const int j = s * 4 + t;  // global K-step 0..15
      if (j + 3 < 16) ISSUE_A_SLOT(j + 3);
      // corrected wait schedule (see header comment):
      if (j <= 11 && (j & 3) != 3)      WAIT_VM(14);  // A(j) oldest in queue
      else if (j == 3 || j == 7 || j == 11 || j == 12) WAIT_VM(6);
      else if (j == 13) WAIT_VM(4);
      else if (j == 14) WAIT_VM(2);
      else              WAIT_VM(0);    // j == 15

      floatx4 x = PF[j & 3][0], y = PF[j & 3][1];
      uint4 uh, ul;
      split_pair(x[0], x[1], uh.x, ul.x);
      split_pair(x[2], x[3], uh.y, ul.y);
      split_pair(y[0], y[1], uh.z, ul.z);
      split_pair(y[2], y[3], uh.w, ul.w);
      bf16x8 Ah = __builtin_bit_cast(bf16x8, uh);
      bf16x8 Al = __builtin_bit_cast(bf16x8, ul);
      const int kl = t * 32;
#pragma unroll
      for (int nt = 0; nt < 4; ++nt) {
        const int boff = (nt * 16 + c) * BROW + kl + quad * 8;
        bf16x8 Bh = *(const bf16x8*)&BhL[boff];
        bf16x8 Bl = *(const bf16x8*)&BlL[boff];
        acc[nt] = __builtin_amdgcn_mfma_f32_16x16x32_bf16(Ah, Bh, acc[nt], 0, 0, 0);
        acc[nt] = __builtin_amdgcn_mfma_f32_16x16x32_bf16(Ah, Bl, acc[nt], 0, 0, 0);
        acc[nt] = __builtin_amdgcn_mfma_f32_16x16x32_bf16(Al, Bh, acc[nt], 0, 0, 0);
      }
    }
    if (s < 3) BARRIER();       // stage-s B tile fully consumed
  }

  // ---- epilogue: C/D layout row = quad*4+reg, col = lane&15 ----
#pragma unroll
  for (int reg = 0; reg < 4; ++reg) {
    float lg[4];  bool val[4];
#pragma unroll
    for (int nt = 0; nt < 4; ++nt) {
      const int n = nt * 16 + c;
      val[nt] = (n < HH);
      lg[nt] = acc[nt][reg] + sBias[n];
    }
    float m = -1e30f;
#pragma unroll
    for (int nt = 0; nt < 4; ++nt) if (val[nt]) m = fmaxf(m, lg[nt]);
#pragma unroll
    for (int d = 1; d < 16; d <<= 1) m = fmaxf(m, __shfl_xor(m, d, 64));

    float s0=0.f,c0=0.f,s1=0.f,c1=0.f,s2=0.f,c2=0.f;
#pragma unroll
    for (int nt = 0; nt < 4; ++nt) {
      const int n = nt * 16 + c;
      float e = val[nt] ? __expf(lg[nt] - m) : 0.f;
      s0 = fmaf(e, sS[n*3+0], s0);  c0 = fmaf(e, sC[n*3+0], c0);
      s1 = fmaf(e, sS[n*3+1], s1);  c1 = fmaf(e, sC[n*3+1], c1);
      s2 = fmaf(e, sS[n*3+2], s2);  c2 = fmaf(e, sC[n*3+2], c2);
    }
#pragma unroll
    for (int d = 1; d < 16; d <<= 1) {
      s0 += __shfl_xor(s0, d, 64);  c0 += __shfl_xor(c0, d, 64);
      s1 += __shfl_xor(s1, d, 64);  c1 += __shfl_xor(c1, d, 64);
      s2 += __shfl_xor(s2, d, 64);  c2 += __shfl_xor(c2, d, 64);
    }
    if (c == 0) {
      const int row = row0 + wid * 16 + quad * 4 + reg;
      const int l  = row >> 7;        // / BT
      const int bb = row & 127;       // % BT
      float* pp = phi_out + (size_t)bb * NSTEP + 3 * l;
      pp[0] = atan2f(s0, c0);
      pp[1] = atan2f(s1, c1);
      pp[2] = atan2f(s2, c2);
    }
  }
}

// ---------- rigid transform (3x3 rotation row-major + translation) ----------
struct Xf { float r[9]; float p[3]; };

__device__ __forceinline__ Xf compose(const Xf& A, const Xf& B) {
  Xf o;
#pragma unroll
  for (int i = 0; i < 3; ++i) {
#pragma unroll
    for (int j = 0; j < 3; ++j) {
      o.r[i*3+j] = fmaf(A.r[i*3+0], B.r[0+j],
                   fmaf(A.r[i*3+1], B.r[3+j],
                        A.r[i*3+2] * B.r[6+j]));
    }
    o.p[i] = fmaf(A.r[i*3+0], B.p[0],
             fmaf(A.r[i*3+1], B.p[1],
             fmaf(A.r[i*3+2], B.p[2], A.p[i])));
  }
  return o;
}

__device__ __forceinline__ Xf make_T(float phi, float st, float ct, float r) {
  float sp = __sinf(phi), cp = __cosf(phi);
  Xf T;
  T.r[0] = ct;      T.r[1] = -st;     T.r[2] = 0.f;
  T.r[3] = cp * st; T.r[4] = ct * cp; T.r[5] = -sp;
  T.r[6] = sp * st; T.r[7] = ct * sp; T.r[8] = cp;
  T.p[0] = r * ct;  T.p[1] = r * T.r[3]; T.p[2] = r * T.r[6];
  return T;
}

__device__ __forceinline__ void set_identity(Xf& X) {
  X.r[0]=1.f; X.r[1]=0.f; X.r[2]=0.f;
  X.r[3]=0.f; X.r[4]=1.f; X.r[5]=0.f;
  X.r[6]=0.f; X.r[7]=0.f; X.r[8]=1.f;
  X.p[0]=0.f; X.p[1]=0.f; X.p[2]=0.f;
}

// ---------- kernel 2: two-level parallel rigid-transform scan ---------------
__global__ __launch_bounds__(256) void k_scan(
    const float* __restrict__ phi, const float* __restrict__ bl,
    const float* __restrict__ ba, float* __restrict__ out) {
  __shared__ Xf wt[4];

  const int b = blockIdx.x;       // chain 0..127
  const int t = threadIdx.x & 63; // lane in wave
  const int w = threadIdx.x >> 6; // wave 0..3
  const int g = threadIdx.x;      // global lane 0..255

  float st[3], ct[3], rr[3];
#pragma unroll
  for (int j = 0; j < 3; ++j) {
    float a = ba[j];
    st[j] = __sinf(a); ct[j] = __cosf(a); rr[j] = bl[j];
  }

  // steps for this lane: g*6 .. g*6+5 ; (g*6+s)%3 == s%3 since 6%3==0
  float f[CH2];
  const float2* ph2 = (const float2*)(phi + (size_t)b * NSTEP + g * CH2);
#pragma unroll
  for (int q = 0; q < CH2/2; ++q) {
    float2 v = ph2[q];
    f[2*q+0] = v.x; f[2*q+1] = v.y;
  }

  Xf Q = make_T(f[0], st[0], ct[0], rr[0]);
#pragma unroll
  for (int s = 1; s < CH2; ++s)
    Q = compose(Q, make_T(f[s], st[s%3], ct[s%3], rr[s%3]));

  // wave-level inclusive scan (left-compose earlier lanes)
#pragma unroll
  for (int d = 1; d < 64; d <<= 1) {
    Xf O;
#pragma unroll
    for (int q = 0; q < 9; ++q) O.r[q] = __shfl_up(Q.r[q], d, 64);
#pragma unroll
    for (int q = 0; q < 3; ++q) O.p[q] = __shfl_up(Q.p[q], d, 64);
    if (t < d) set_identity(O);
    Q = compose(O, Q);
  }

  // cross-wave totals
  if (t == 63) wt[w] = Q;
  __syncthreads();

  // wave-local exclusive prefix
  Xf E;
#pragma unroll
  for (int q = 0; q < 9; ++q) E.r[q] = __shfl_up(Q.r[q], 1, 64);
#pragma unroll
  for (int q = 0; q < 3; ++q) E.p[q] = __shfl_up(Q.p[q], 1, 64);
  if (t == 0) set_identity(E);

  Xf S0;
  S0.r[0] = 0.f;                  S0.r[1] = 0.816496580927726f;   S0.r[2] = 0.5773502691896258f;
  S0.r[3] = -0.7071067811865475f; S0.r[4] = -0.4082482904638631f; S0.r[5] = 0.5773502691896258f;
  S0.r[6] = 0.7071067811865475f;  S0.r[7] = -0.4082482904638631f; S0.r[8] = 0.5773502691896258f;
  S0.p[0] = 0.f; S0.p[1] = 0.f; S0.p[2] = 1.f;

  // SP = S0 ∘ (wt[0] ∘ ... ∘ wt[w-1])  (wave-uniform, <=3 composes)
  Xf SP = S0;
#pragma unroll
  for (int i = 0; i < 3; ++i)
    if (i < w) SP = compose(SP, wt[i]);

  Xf cur = compose(SP, E);

  float* op = out + (size_t)(g * CH2) * (BT * 3) + b * 3;
#pragma unroll
  for (int s = 0; s < CH2; ++s) {
    cur = compose(cur, make_T(f[s], st[s%3], ct[s%3], rr[s%3]));
    op[(size_t)s * (BT*3) + 0] = cur.p[0];
    op[(size_t)s * (BT*3) + 1] = cur.p[1];
    op[(size_t)s * (BT*3) + 2] = cur.p[2];
  }
}

// ---------- launch ---------------------------------------------------------
extern "C" void kernel_launch(void* const* d_in, const int* in_sizes, int n_in,
                              void* d_out, int out_size, void* d_ws, size_t ws_size,
                              hipStream_t stream) {
  const float* inp      = (const float*)d_in[0];
  const float* W        = (const float*)d_in[1];
  const float* bias     = (const float*)d_in[2];
  const float* alphabet = (const float*)d_in[3];
  const float* bl       = (const float*)d_in[4];
  const float* ba       = (const float*)d_in[5];
  float* out = (float*)d_out;

  float* phi = (float*)d_ws;   // 786432 B

  k_phi<<<dim3((LSEQ*BT)/MTILE), dim3(256), 0, stream>>>(inp, W, bias, alphabet, phi);
  k_scan<<<dim3(BT), dim3(256), 0, stream>>>(phi, bl, ba, out);
}